// Round 20
// baseline (6202.295 us; speedup 1.0000x reference)
//
#include <hip/hip_runtime.h>
#include <hip/hip_bf16.h>
#include <hip/hip_fp16.h>

#define B_ 4096
#define T_ 24
#define F_ 12
#define H_ 512
#define GH_ 2048   // 4*H
#define ZW_ 6400   // F*H + 256
#define L2E 1.44269504088896340736f

// XOR swizzle (16B-fragment granularity, bijective within a 512-short row)
#define SWZ(row, elem) ((elem) ^ (((row) & 15) << 3))

typedef __attribute__((ext_vector_type(8))) short short8;
typedef __attribute__((ext_vector_type(4))) float f32x4;
typedef __attribute__((ext_vector_type(2))) __fp16 f16x2;   // matches cvt_pkrtz return

__device__ __forceinline__ short f2bf(float f) {
    union { float f; unsigned int u; } v; v.f = f;
    unsigned int u = v.u;
    unsigned int r = (u + 0x7FFFu + ((u >> 16) & 1u)) >> 16;
    return (short)r;
}
__device__ __forceinline__ float bf2f(short b) {
    union { unsigned int u; float f; } v; v.u = ((unsigned int)(unsigned short)b) << 16;
    return v.f;
}
__device__ __forceinline__ float fastrcp(float x) { return __builtin_amdgcn_rcpf(x); }
__device__ __forceinline__ float ex2(float x) { return __builtin_amdgcn_exp2f(x); }

// ---------------------------------------------------------------- convert
// Whh packed to MFMA B-fragment order, PRE-SCALED by log2e (gate g=2: 2*log2e)
// so the epilogue uses native v_exp_f32 (2^x):
//   Wpk[(((f*32 + jb)*16 + kk)*4 + g)*512 + l*8 + e]
//     = bf16( sc[g] * Whh[f][g*512 + jb*16 + (l&15)][kk*32 + (l>>4)*8 + e] )
// Wx: x-part B-fragments (wx0, wx1, bias_hi, bias_lo, wx0, 0,0,0) on lq==0.
__global__ void k_convert(const float* Whh, const float* dW1, const float* dW2,
                          const float* bih, const float* bhh, const float* Wih,
                          const float* sW1, const float* sW2, const float* sW3,
                          short* Wpk, short* Wx, short* odW1, short* odW2,
                          float* sW1T, float* sW2T, float* sW3T) {
    const int N2 = 1024 * ZW_;             // 6,553,600
    const int N3 = 1024 * 1024;
    const int N4 = F_ * 32 * 16 * 4 * 64;  // Wpk fragments of 8
    const int N5 = F_ * 32 * 4 * 64;       // Wx fragments of 8
    int idx = blockIdx.x * blockDim.x + threadIdx.x;
    int stride = gridDim.x * blockDim.x;
    for (int i = idx; i < N4; i += stride) {
        int l  = i & 63;
        int g  = (i >> 6) & 3;
        int kk = (i >> 8) & 15;
        int jb = (i >> 12) & 31;
        int f  = i >> 17;
        float sc = (g == 2) ? 2.f * L2E : L2E;
        int row = g * 512 + jb * 16 + (l & 15);
        int col = kk * 32 + (l >> 4) * 8;
        const float* src = Whh + ((size_t)f * GH_ + row) * H_ + col;
        short tmp[8];
        #pragma unroll
        for (int e = 0; e < 8; e++) tmp[e] = f2bf(src[e] * sc);
        *(short8*)(Wpk + (size_t)i * 8) = *(short8*)tmp;
    }
    for (int i = idx; i < N5; i += stride) {
        int l  = i & 63;
        int g  = (i >> 6) & 3;
        int jb = (i >> 8) & 31;
        int f  = i >> 13;
        short tmp[8] = {0, 0, 0, 0, 0, 0, 0, 0};
        if ((l >> 4) == 0) {
            float sc = (g == 2) ? 2.f * L2E : L2E;
            int col = g * 512 + jb * 16 + (l & 15);
            float w0 = Wih[((size_t)f * GH_ + col) * 2] * sc;
            float w1 = Wih[((size_t)f * GH_ + col) * 2 + 1] * sc;
            float bs = (bih[f * GH_ + col] + bhh[f * GH_ + col]) * sc;
            short bh = f2bf(bs);
            short bl = f2bf(bs - bf2f(bh));
            short w0b = f2bf(w0);
            tmp[0] = w0b; tmp[1] = f2bf(w1); tmp[2] = bh; tmp[3] = bl; tmp[4] = w0b;
        }
        *(short8*)(Wx + (size_t)i * 8) = *(short8*)tmp;
    }
    for (int i = idx; i < N2; i += stride) odW1[i] = f2bf(dW1[i]);
    for (int i = idx; i < N3; i += stride) odW2[i] = f2bf(dW2[i]);
    for (int i = idx; i < 64 * 256; i += stride) {      // sW1T[i][t] = sW1[t][i]
        int r = i >> 8, t = i & 255;
        sW1T[i] = sW1[t * 64 + r];
    }
    for (int i = idx; i < 256 * 256; i += stride) {
        int r = i >> 8, t = i & 255;
        sW2T[i] = sW2[t * 256 + r];
        sW3T[i] = sW3[t * 256 + r];
    }
}

// ---------------------------------------------------------------- LSTM sub-step
// One 16-col j-subtile for one wave; wave owns 16 rows x 128 cols (8 subtiles,
// 1 rowfrag). TWIN-WAVE design: waves w and w+4 share an EU and read
// IDENTICAL weight addresses in near-lockstep (same wc) -> L1/MSHR merges
// the duplicate line requests, halving per-CU L2 weight bytes (the measured
// binding term: 37K of 58K cyc/step in r17). Register budget ~91 = r17's 92:
// acc 16 (1 rowfrag) + cpk 16 + ax 4 + unroll-2 window 40 + addr ~15.
// kk unroll 2 (HARD CAP, r16's unroll-3 spilled).
template<int S>
__device__ __forceinline__ void lstm_step_sub(
    const short* hread, short* hwrite, f16x2 (&cpk)[8][2],
    const short* Wb, const short* WxS,
    const short8& ax,
    int rowbase, int l, int l15, int lq, int wc)
{
    const short* Ws = Wb + ((size_t)S << 15) + l * 8;
    const f32x4 zero = {0.f, 0.f, 0.f, 0.f};
    f32x4 acc[4];   // [gate] = 16 f32
    #pragma unroll
    for (int g = 0; g < 4; g++) {
        short8 bx = *(const short8*)(WxS + S * 2048 + g * 512);
        acc[g] = __builtin_amdgcn_mfma_f32_16x16x32_bf16(ax, bx, zero, 0, 0, 0);
    }
    // K loop: 512 = 16 x 32; unroll 2 (PROVEN cap -- do not raise)
    #pragma unroll 2
    for (int kk = 0; kk < 16; kk++) {
        int k = kk * 32 + lq * 8;
        int row = rowbase + l15;
        short8 a = *(const short8*)&hread[SWZ(row, row * 512 + k)];
        short8 bfr[4];
        #pragma unroll
        for (int g = 0; g < 4; g++)
            bfr[g] = *(const short8*)(Ws + (kk * 4 + g) * 512);
        #pragma unroll
        for (int g = 0; g < 4; g++)
            acc[g] = __builtin_amdgcn_mfma_f32_16x16x32_bf16(a, bfr[g], acc[g], 0, 0, 0);
    }
    // cell update + h write. Common-denominator forms (5 exp + 2 rcp/cell):
    //   ef=2^f, ei=2^i, eg=2^{2g}: cn = [ef*ei1*eg1*c + ei*(eg-1)*ef1]/(ef1*ei1*eg1)
    //   hn = eo*(ec-1) / ((eo+1)*(ec+1)),  ec = 2^{cn*2*log2e}
    int j = wc * 128 + S * 16 + l15;
    #pragma unroll
    for (int pi = 0; pi < 2; pi++) {
        f16x2 cold = cpk[S][pi];
        float cn01[2], hn01[2];
        #pragma unroll
        for (int q = 0; q < 2; q++) {
            int p = pi * 2 + q;
            float iv = acc[0][p], fv = acc[1][p];
            float gv = acc[2][p], ov = acc[3][p];
            float ef = ex2(fv), ei = ex2(iv), eg = ex2(gv);
            float ef1 = ef + 1.f, ei1 = ei + 1.f, eg1 = eg + 1.f;
            float e12 = ei1 * eg1;
            float cn = (ef * e12 * (float)cold[q] + ei * (eg - 1.f) * ef1)
                     * fastrcp(ef1 * e12);
            cn01[q] = cn;
            float eo = ex2(ov), ec = ex2(cn * (2.f * L2E));
            hn01[q] = eo * (ec - 1.f) * fastrcp((eo + 1.f) * (ec + 1.f));
        }
        cpk[S][pi] = __builtin_amdgcn_cvt_pkrtz(cn01[0], cn01[1]);
        unsigned hp;
        asm("v_cvt_pk_bf16_f32 %0, %1, %2" : "=v"(hp) : "v"(hn01[0]), "v"(hn01[1]));
        int row0 = rowbase + lq * 4 + pi * 2;
        hwrite[SWZ(row0, row0 * 512 + j)]           = (short)(hp & 0xffffu);
        hwrite[SWZ(row0 + 1, (row0 + 1) * 512 + j)] = (short)(hp >> 16);
    }
}

// grid 1536 (12 features x 128 batch-tiles of 32 rows), 512 threads (8 waves:
// 2 row-groups x 4 col-groups; wr = w>>2, wc = w&3 -> twins w,w+4 share an
// EU and a weight stream). h double-buffered bf16 in LDS (2x32KB, swizzled);
// c in 16 packed-f16 regs. r17's lean epilogue; TRIPWIRE: WRITE>=65MB=spill.
__global__ __launch_bounds__(512, 2)
void k_lstm(const short* __restrict__ Wpk,   // packed+prescaled, see k_convert
            const short* __restrict__ Wx,    // x-part fragments (prescaled)
            const float* __restrict__ tfeat, // [B][T][F]
            const float* __restrict__ tmask,
            const float* __restrict__ h0,    // [F][B][H]
            const float* __restrict__ c0,
            short* __restrict__ Z)           // [B][6400] bf16
{
    __shared__ __align__(16) short hbuf[2][32 * 512];   // 2 x 32KB
    __shared__ float xv[2][32], xm[2][32];

    int bid = blockIdx.x;
    int wg = (bid & 7) * 192 + (bid >> 3);   // XCD swizzle (1536 = 8*192, bijective)
    int f = wg >> 7;
    int b0 = (wg & 127) * 32;
    int tid = threadIdx.x;
    int w = tid >> 6;
    int wr = w >> 2;            // row-group 0/1 (twins w, w+4 share an EU)
    int wc = w & 3;             // col-group 0..3
    int rowbase = wr * 16;
    int l = tid & 63;
    int l15 = l & 15, lq = l >> 4;

    // stage h0 -> hbuf[0] (bf16, swizzled): 32 rows x 512 cols
    {
        int row = tid >> 4, cg = (tid & 15) * 32;
        const float* src = h0 + ((size_t)f * B_ + b0 + row) * H_ + cg;
        #pragma unroll
        for (int i = 0; i < 32; i += 8) {
            short tmp[8];
            #pragma unroll
            for (int j = 0; j < 8; j++) tmp[j] = f2bf(src[i + j]);
            *(short8*)&hbuf[0][SWZ(row, row * 512 + cg + i)] = *(short8*)tmp;
        }
    }
    if (tid < 32)       xv[0][tid]      = tfeat[(size_t)(b0 + tid) * (T_ * F_) + f];
    else if (tid < 64)  xm[0][tid - 32] = tmask[(size_t)(b0 + tid - 32) * (T_ * F_) + f];

    // c0 -> packed f16 regs: cpk[s][pi] holds cells p = 2pi, 2pi+1 of subtile s
    f16x2 cpk[8][2];
    #pragma unroll
    for (int s = 0; s < 8; s++) {
        int j = wc * 128 + s * 16 + l15;
        const float* cp = c0 + ((size_t)f * B_ + b0 + rowbase + lq * 4) * H_ + j;
        #pragma unroll
        for (int pi = 0; pi < 2; pi++)
            cpk[s][pi] = __builtin_amdgcn_cvt_pkrtz(
                cp[(size_t)(pi * 2) * H_], cp[(size_t)(pi * 2 + 1) * H_]);
    }
    __syncthreads();

    const short* Wb  = Wpk + (((size_t)f * 32 + wc * 8) << 15);
    const short* WxS = Wx + ((size_t)(f * 32 + wc * 8) * 4) * 512 + l * 8;

    #pragma unroll 1
    for (int t = 0; t < T_; t++) {
        int rb = t & 1, wb = rb ^ 1;
        // prefetch x(t+1) into the other buffer (ordered by end-of-step barrier)
        if (t < T_ - 1) {
            if (tid < 32)      xv[wb][tid]      = tfeat[(size_t)(b0 + tid) * (T_ * F_) + (t + 1) * F_ + f];
            else if (tid < 64) xm[wb][tid - 32] = tmask[(size_t)(b0 + tid - 32) * (T_ * F_) + (t + 1) * F_ + f];
        }
        // build x A-fragment ONCE per step (identical across the 8 subtiles)
        short8 ax = {0, 0, 0, 0, 0, 0, 0, 0};
        if (lq == 0) {
            int row = rowbase + l15;
            float xvf = xv[rb][row], xmf = xm[rb][row];
            short hi = f2bf(xvf);
            ax[0] = hi; ax[1] = f2bf(xmf);
            ax[2] = (short)0x3F80; ax[3] = (short)0x3F80;
            ax[4] = f2bf(xvf - bf2f(hi));
        }
        const short* hr = hbuf[rb];
        short*       hw = hbuf[wb];
        lstm_step_sub<0>(hr, hw, cpk, Wb, WxS, ax, rowbase, l, l15, lq, wc);
        lstm_step_sub<1>(hr, hw, cpk, Wb, WxS, ax, rowbase, l, l15, lq, wc);
        lstm_step_sub<2>(hr, hw, cpk, Wb, WxS, ax, rowbase, l, l15, lq, wc);
        lstm_step_sub<3>(hr, hw, cpk, Wb, WxS, ax, rowbase, l, l15, lq, wc);
        lstm_step_sub<4>(hr, hw, cpk, Wb, WxS, ax, rowbase, l, l15, lq, wc);
        lstm_step_sub<5>(hr, hw, cpk, Wb, WxS, ax, rowbase, l, l15, lq, wc);
        lstm_step_sub<6>(hr, hw, cpk, Wb, WxS, ax, rowbase, l, l15, lq, wc);
        lstm_step_sub<7>(hr, hw, cpk, Wb, WxS, ax, rowbase, l, l15, lq, wc);
        __syncthreads();
    }

    // final h (in hbuf[0], T even) -> Z columns [f*512, f*512+512)
    {
        int row = tid >> 4, cg = (tid & 15) * 32;
        short* dst = Z + (size_t)(b0 + row) * ZW_ + f * H_ + cg;
        #pragma unroll
        for (int i = 0; i < 32; i += 8)
            *(short8*)(dst + i) = *(const short8*)&hbuf[0][SWZ(row, row * 512 + cg + i)];
    }
}

// ---------------------------------------------------------------- static MLP
__global__ void k_static(const float* __restrict__ X,
                         const float* __restrict__ sW1T, const float* __restrict__ sb1,
                         const float* __restrict__ sW2T, const float* __restrict__ sb2,
                         const float* __restrict__ sW3T, const float* __restrict__ sb3,
                         short* __restrict__ Z) {
    __shared__ float xs[64], s1[256], s2[256];
    int row = blockIdx.x, tid = threadIdx.x;
    if (tid < 64) xs[tid] = X[row * 64 + tid];
    __syncthreads();
    float a = sb1[tid];
    for (int i = 0; i < 64; i++) a += xs[i] * sW1T[i * 256 + tid];
    s1[tid] = fmaxf(a, 0.f);
    __syncthreads();
    a = sb2[tid];
    for (int i = 0; i < 256; i++) a += s1[i] * sW2T[i * 256 + tid];
    s2[tid] = fmaxf(a, 0.f);
    __syncthreads();
    a = sb3[tid];
    for (int i = 0; i < 256; i++) a += s2[i] * sW3T[i * 256 + tid];
    Z[(size_t)row * ZW_ + F_ * H_ + tid] = f2bf(fmaxf(a, 0.f));
}

// ---------------------------------------------------------------- GEMM + bias + relu
__global__ __launch_bounds__(256, 2)
void k_gemm_relu(const short* __restrict__ A, const short* __restrict__ W,
                 const float* __restrict__ bias, short* __restrict__ C,
                 int M, int N, int K) {
    __shared__ __align__(16) short at[128 * 128];
    int tid = threadIdx.x;
    int wid = tid >> 6, l = tid & 63, l15 = l & 15, lq = l >> 4;
    int wm = wid >> 1, wn = wid & 1;
    int mb = blockIdx.x * 128, nb = blockIdx.y * 128;
    f32x4 acc[4][4];   // [colfrag][rowfrag]
    #pragma unroll
    for (int n = 0; n < 4; n++)
        #pragma unroll
        for (int r = 0; r < 4; r++)
            acc[n][r] = (f32x4){0.f, 0.f, 0.f, 0.f};

    #pragma unroll 1
    for (int kc = 0; kc < K; kc += 128) {
        {   // stage A tile 128x128 bf16 (swizzled)
            int row = tid >> 1, off = (tid & 1) * 64;
            const short* src = A + (size_t)(mb + row) * K + kc + off;
            #pragma unroll
            for (int i = 0; i < 64; i += 8) {
                short8 v = *(const short8*)(src + i);
                int elem = (row * 128 + off + i) ^ ((row & 7) << 3);
                *(short8*)&at[elem] = v;
            }
        }
        __syncthreads();
        #pragma unroll
        for (int kk = 0; kk < 4; kk++) {
            int k = kk * 32 + lq * 8;
            short8 a[4], bfr[4];
            #pragma unroll
            for (int r = 0; r < 4; r++) {
                int row = wm * 64 + 16 * r + l15;
                int elem = (row * 128 + k) ^ ((row & 7) << 3);
                a[r] = *(const short8*)&at[elem];
            }
            #pragma unroll
            for (int n = 0; n < 4; n++)
                bfr[n] = *(const short8*)(W + (size_t)(nb + wn * 64 + 16 * n + l15) * K + kc + k);
            #pragma unroll
            for (int n = 0; n < 4; n++)
                #pragma unroll
                for (int r = 0; r < 4; r++)
                    acc[n][r] = __builtin_amdgcn_mfma_f32_16x16x32_bf16(a[r], bfr[n], acc[n][r], 0, 0, 0);
        }
        __syncthreads();
    }
    #pragma unroll
    for (int n = 0; n < 4; n++) {
        int col = nb + wn * 64 + 16 * n + l15;
        float bv = bias[col];
        #pragma unroll
        for (int r = 0; r < 4; r++)
            #pragma unroll
            for (int p = 0; p < 4; p++) {
                int row = mb + wm * 64 + 16 * r + lq * 4 + p;
                C[(size_t)row * N + col] = f2bf(fmaxf(acc[n][r][p] + bv, 0.f));
            }
    }
}

// ---------------------------------------------------------------- head layer 3 + BCE partials
__global__ void k_head3(const short* __restrict__ Z2, const float* __restrict__ W3,
                        const float* __restrict__ b3, const float* __restrict__ tgt,
                        float* __restrict__ out, float* __restrict__ lsum) {
    __shared__ float ls[32];
    int tid = threadIdx.x, wv = tid >> 6, l = tid & 63;
    int rsub = l >> 3, ks = l & 7;
    int row = blockIdx.x * 32 + wv * 8 + rsub;
    const short* z = Z2 + (size_t)row * 1024 + ks * 128;
    const float* w0 = W3 + ks * 128;
    const float* w1 = W3 + 1024 + ks * 128;
    float a0 = 0.f, a1 = 0.f;
    for (int i = 0; i < 128; i += 8) {
        short8 zv = *(const short8*)(z + i);
        #pragma unroll
        for (int j = 0; j < 8; j++) {
            float zf = bf2f(zv[j]);
            a0 += zf * w0[i + j];
            a1 += zf * w1[i + j];
        }
    }
    a0 += __shfl_xor(a0, 1); a0 += __shfl_xor(a0, 2); a0 += __shfl_xor(a0, 4);
    a1 += __shfl_xor(a1, 1); a1 += __shfl_xor(a1, 2); a1 += __shfl_xor(a1, 4);
    if (ks == 0) {
        float p0 = fmaxf(a0 + b3[0], 0.f), p1 = fmaxf(a1 + b3[1], 0.f);
        out[row * 2] = p0; out[row * 2 + 1] = p1;
        float t0 = tgt[row * 2], t1 = tgt[row * 2 + 1];
        ls[wv * 8 + rsub] = (p0 - p0 * t0 + __logf(1.f + __expf(-p0)))
                          + (p1 - p1 * t1 + __logf(1.f + __expf(-p1)));
    }
    __syncthreads();
    if (tid == 0) {
        float s = 0.f;
        for (int i = 0; i < 32; i++) s += ls[i];
        lsum[blockIdx.x] = s;
    }
}

__global__ void k_loss_final(const float* __restrict__ lsum, float* __restrict__ out) {
    int l = threadIdx.x;   // 64 threads
    float v = lsum[l] + lsum[l + 64];
    for (int m = 1; m < 64; m <<= 1) v += __shfl_xor(v, m);
    if (l == 0) out[B_ * 2] = v / (float)(B_ * 2);
}

// ---------------------------------------------------------------- launch
extern "C" void kernel_launch(void* const* d_in, const int* in_sizes, int n_in,
                              void* d_out, int out_size, void* d_ws, size_t ws_size,
                              hipStream_t stream) {
    const float* sfeat = (const float*)d_in[0];
    const float* tfeat = (const float*)d_in[1];
    const float* tmask = (const float*)d_in[2];
    const float* tgt   = (const float*)d_in[3];
    const float* h0    = (const float*)d_in[4];
    const float* c0    = (const float*)d_in[5];
    const float* Wih   = (const float*)d_in[6];
    const float* Whh   = (const float*)d_in[7];
    const float* bih   = (const float*)d_in[8];
    const float* bhh   = (const float*)d_in[9];
    const float* sW1   = (const float*)d_in[10];
    const float* sb1   = (const float*)d_in[11];
    const float* sW2   = (const float*)d_in[12];
    const float* sb2   = (const float*)d_in[13];
    const float* sW3   = (const float*)d_in[14];
    const float* sb3   = (const float*)d_in[15];
    const float* dW1   = (const float*)d_in[16];
    const float* db1   = (const float*)d_in[17];
    const float* dW2   = (const float*)d_in[18];
    const float* db2   = (const float*)d_in[19];
    const float* dW3   = (const float*)d_in[20];
    const float* db3   = (const float*)d_in[21];

    char* ws = (char*)d_ws;
    size_t off = 0;
    short* Wpk    = (short*)(ws + off); off += (size_t)F_ * GH_ * H_ * 2;       // 25,165,824
    short* Wx     = (short*)(ws + off); off += (size_t)F_ * 32 * 4 * 512 * 2;   //  1,572,864
    short* dW1_bf = (short*)(ws + off); off += (size_t)1024 * ZW_ * 2;          // 13,107,200
    short* dW2_bf = (short*)(ws + off); off += (size_t)1024 * 1024 * 2;         //  2,097,152
    float* sW1T   = (float*)(ws + off); off += (size_t)64 * 256 * 4;
    float* sW2T   = (float*)(ws + off); off += (size_t)256 * 256 * 4;
    float* sW3T   = (float*)(ws + off); off += (size_t)256 * 256 * 4;
    short* Z      = (short*)(ws + off); off += (size_t)B_ * ZW_ * 2;            // 52,428,800
    short* Z1     = (short*)(ws + off); off += (size_t)B_ * 1024 * 2;
    short* Z2     = (short*)(ws + off); off += (size_t)B_ * 1024 * 2;
    float* lsum   = (float*)(ws + off); off += 128 * 4;

    float* out = (float*)d_out;

    k_convert<<<2048, 256, 0, stream>>>(Whh, dW1, dW2, bih, bhh, Wih, sW1, sW2, sW3,
                                        Wpk, Wx, dW1_bf, dW2_bf, sW1T, sW2T, sW3T);
    k_lstm<<<1536, 512, 0, stream>>>(Wpk, Wx, tfeat, tmask, h0, c0, Z);
    k_static<<<4096, 256, 0, stream>>>(sfeat, sW1T, sb1, sW2T, sb2, sW3T, sb3, Z);
    k_gemm_relu<<<dim3(32, 8), 256, 0, stream>>>(Z, dW1_bf, db1, Z1, B_, 1024, ZW_);
    k_gemm_relu<<<dim3(32, 8), 256, 0, stream>>>(Z1, dW2_bf, db2, Z2, B_, 1024, 1024);
    k_head3<<<128, 256, 0, stream>>>(Z2, dW3, db3, tgt, out, lsum);
    k_loss_final<<<1, 64, 0, stream>>>(lsum, out);
}

// Round 21
// 2656.436 us; speedup vs baseline: 2.3348x; 2.3348x over previous
//
#include <hip/hip_runtime.h>
#include <hip/hip_bf16.h>
#include <hip/hip_fp16.h>

#define B_ 4096
#define T_ 24
#define F_ 12
#define H_ 512
#define GH_ 2048   // 4*H
#define ZW_ 6400   // F*H + 256
#define L2E 1.44269504088896340736f

typedef __attribute__((ext_vector_type(8))) short short8;
typedef __attribute__((ext_vector_type(4))) float f32x4;
typedef __attribute__((ext_vector_type(4))) int int4v;
typedef __attribute__((ext_vector_type(2))) __fp16 f16x2;
typedef signed char i8;

// byte-level XOR swizzle, 16B granularity, bijective within a 512-byte row
#define SWZ8(row, byte) ((byte) ^ (((row) & 15) << 4))

__device__ __forceinline__ short f2bf(float f) {
    union { float f; unsigned int u; } v; v.f = f;
    unsigned int u = v.u;
    unsigned int r = (u + 0x7FFFu + ((u >> 16) & 1u)) >> 16;
    return (short)r;
}
__device__ __forceinline__ float fastrcp(float x) { return __builtin_amdgcn_rcpf(x); }
__device__ __forceinline__ float ex2(float x) { return __builtin_amdgcn_exp2f(x); }

// ---------------------------------------------------------------- scales
// One thread per gate-row: s = max|Whh_row|/127; wxb4[row] = (wx0*sc, wx1*sc,
// bias*sc, s*sc/127) with sc = log2e (gate 2: 2*log2e) folded in for ex2.
__global__ void k_scales(const float* Whh, const float* Wih,
                         const float* bih, const float* bhh,
                         float* sscale, float* wxb4) {
    int idx = blockIdx.x * blockDim.x + threadIdx.x;
    if (idx >= F_ * GH_) return;
    int row = idx % GH_;
    int g = row >> 9;
    const float* wr = Whh + (size_t)idx * H_;
    float mx = 1e-8f;
    for (int k = 0; k < H_; k++) mx = fmaxf(mx, fabsf(wr[k]));
    float s = mx * (1.f / 127.f);
    sscale[idx] = s;
    float sc = (g == 2) ? 2.f * L2E : L2E;
    float4 v;
    v.x = Wih[(size_t)idx * 2] * sc;
    v.y = Wih[(size_t)idx * 2 + 1] * sc;
    v.z = (bih[idx] + bhh[idx]) * sc;
    v.w = s * sc * (1.f / 127.f);
    ((float4*)wxb4)[idx] = v;
}

// ---------------------------------------------------------------- convert
// Whh -> int8 MFMA B-fragments (K=64):
//   Wpk8[(((f*32+jb)*8+kk)*4+g)*1024 + l*16 + e]
//     = q( Whh[f][g*512+jb*16+(l&15)][kk*64+(l>>4)*16+e] / s_row )
__global__ void k_convert(const float* Whh, const float* dW1, const float* dW2,
                          const float* sW1, const float* sW2, const float* sW3,
                          const float* sscale,
                          i8* Wpk8, short* odW1, short* odW2,
                          float* sW1T, float* sW2T, float* sW3T) {
    const int N2 = 1024 * ZW_;
    const int N3 = 1024 * 1024;
    const int N4 = F_ * 32 * 8 * 4 * 64;   // 786,432 fragments of 16B
    int idx = blockIdx.x * blockDim.x + threadIdx.x;
    int stride = gridDim.x * blockDim.x;
    for (int i = idx; i < N4; i += stride) {
        int l  = i & 63;
        int g  = (i >> 6) & 3;
        int kk = (i >> 8) & 7;
        int jb = (i >> 11) & 31;
        int f  = i >> 16;
        int row = g * 512 + jb * 16 + (l & 15);
        int col = kk * 64 + (l >> 4) * 16;
        const float* src = Whh + ((size_t)f * GH_ + row) * H_ + col;
        float inv = fastrcp(sscale[f * GH_ + row]);
        i8 tmp[16];
        #pragma unroll
        for (int e = 0; e < 16; e++) {
            float q = rintf(src[e] * inv);
            q = fminf(fmaxf(q, -127.f), 127.f);
            tmp[e] = (i8)(int)q;
        }
        *(int4v*)(Wpk8 + (size_t)i * 16) = *(int4v*)tmp;
    }
    for (int i = idx; i < N2; i += stride) odW1[i] = f2bf(dW1[i]);
    for (int i = idx; i < N3; i += stride) odW2[i] = f2bf(dW2[i]);
    for (int i = idx; i < 64 * 256; i += stride) {
        int r = i >> 8, t = i & 255;
        sW1T[i] = sW1[t * 64 + r];
    }
    for (int i = idx; i < 256 * 256; i += stride) {
        int r = i >> 8, t = i & 255;
        sW2T[i] = sW2[t * 256 + r];
        sW3T[i] = sW3[t * 256 + r];
    }
}

// ---------------------------------------------------------------- LSTM sub-step
// One 16-col j-subtile for one wave, 32-row tile (2 rowfrags), int8 K=64:
// 8 kk x 4 gates x 2 rf = 64 MFMA per subtile; i32 exact accumulation;
// dequant + exact f32 x-part/bias in epilogue (wxb4); kk unroll 2 (HARD CAP).
template<int S>
__device__ __forceinline__ void lstm_step_sub(
    const i8* hread, i8* hwrite, f16x2 (&cpk)[4][4],
    const i8* Wb, const float4* wxbf,
    const float* xvp, const float* xmp,
    float hs, short* zb,
    int l, int l15, int lq, int w)
{
    const i8* Ws = Wb + ((size_t)S << 15) + l * 16;   // 8kk*4g*1KB per subtile
    int4v acc[4][2];
    #pragma unroll
    for (int g = 0; g < 4; g++)
        #pragma unroll
        for (int r = 0; r < 2; r++)
            acc[g][r] = (int4v){0, 0, 0, 0};
    #pragma unroll 2
    for (int kk = 0; kk < 8; kk++) {
        int k = kk * 64 + lq * 16;
        int4v a[2], bfr[4];
        #pragma unroll
        for (int r = 0; r < 2; r++) {
            int row = r * 16 + l15;
            a[r] = *(const int4v*)&hread[row * 512 + SWZ8(row, k)];
        }
        #pragma unroll
        for (int g = 0; g < 4; g++)
            bfr[g] = *(const int4v*)(Ws + (kk * 4 + g) * 1024);
        #pragma unroll
        for (int g = 0; g < 4; g++)
            #pragma unroll
            for (int r = 0; r < 2; r++)
                acc[g][r] = __builtin_amdgcn_mfma_i32_16x16x64_i8(a[r], bfr[g], acc[g][r], 0, 0, 0);
    }
    int j = w * 64 + S * 16 + l15;
    float4 wb0 = wxbf[0 * 512 + j], wb1 = wxbf[1 * 512 + j];
    float4 wb2 = wxbf[2 * 512 + j], wb3 = wxbf[3 * 512 + j];
    float d0 = wb0.w * hs, d1 = wb1.w * hs, d2 = wb2.w * hs, d3 = wb3.w * hs;
    #pragma unroll
    for (int r = 0; r < 2; r++) {
        #pragma unroll
        for (int pi = 0; pi < 2; pi++) {
            f16x2 cold = cpk[S][r * 2 + pi];
            float cn01[2];
            #pragma unroll
            for (int q = 0; q < 2; q++) {
                int p = pi * 2 + q;
                int row = r * 16 + lq * 4 + p;
                float xvf = xvp[row], xmf = xmp[row];
                float iv = (float)acc[0][r][p] * d0 + wb0.x * xvf + wb0.y * xmf + wb0.z;
                float fv = (float)acc[1][r][p] * d1 + wb1.x * xvf + wb1.y * xmf + wb1.z;
                float gv = (float)acc[2][r][p] * d2 + wb2.x * xvf + wb2.y * xmf + wb2.z;
                float ov = (float)acc[3][r][p] * d3 + wb3.x * xvf + wb3.y * xmf + wb3.z;
                float ef = ex2(fv), ei = ex2(iv), eg = ex2(gv);
                float ef1 = ef + 1.f, ei1 = ei + 1.f, eg1 = eg + 1.f;
                float e12 = ei1 * eg1;
                float cn = (ef * e12 * (float)cold[q] + ei * (eg - 1.f) * ef1)
                         * fastrcp(ef1 * e12);
                cn01[q] = cn;
                float eo = ex2(ov), ec = ex2(cn * (2.f * L2E));
                float hn = eo * (ec - 1.f) * fastrcp((eo + 1.f) * (ec + 1.f));
                hwrite[row * 512 + SWZ8(row, j)] = (i8)(int)rintf(hn * 127.f);
                if (zb) zb[(size_t)row * ZW_ + j] = f2bf(hn);   // last step: exact bf16 -> Z
            }
            cpk[S][r * 2 + pi] = __builtin_amdgcn_cvt_pkrtz(cn01[0], cn01[1]);
        }
    }
}

// grid 1536 (12 features x 128 batch-tiles of 32 rows), 512 threads (8 waves).
// h double-buffered int8 in LDS (2x16KB, swizzled); c in 16 packed-f16 regs;
// weights int8 (HALVED L2 stream: 36.9GB total, ~1.07ms floor) streamed in
// packed K=64 fragment order; i32 MFMA accumulation (exact).
// h0 (unbounded randn) uses scale 8/127 on t=0 only (hs multiplier).
__global__ __launch_bounds__(512, 2)
void k_lstm(const i8* __restrict__ Wpk8,
            const float* __restrict__ wxb4,  // [F*2048] float4: wx0,wx1,bias,dequant
            const float* __restrict__ tfeat, // [B][T][F]
            const float* __restrict__ tmask,
            const float* __restrict__ h0,    // [F][B][H]
            const float* __restrict__ c0,
            short* __restrict__ Z)           // [B][6400] bf16
{
    __shared__ __align__(16) i8 hbuf[2][32 * 512];   // 2 x 16KB
    __shared__ float xv[2][32], xm[2][32];

    int bid = blockIdx.x;
    int wg = (bid & 7) * 192 + (bid >> 3);   // XCD swizzle (1536 = 8*192, bijective)
    int f = wg >> 7;
    int b0 = (wg & 127) * 32;
    int tid = threadIdx.x;
    int w = tid >> 6;
    int l = tid & 63;
    int l15 = l & 15, lq = l >> 4;

    // stage h0 -> hbuf[0] (int8, scale 8/127, swizzled): 32 rows x 512 cols
    {
        int row = tid >> 4, cg = (tid & 15) * 32;
        const float* src = h0 + ((size_t)f * B_ + b0 + row) * H_ + cg;
        #pragma unroll
        for (int i = 0; i < 32; i += 16) {
            i8 tmp[16];
            #pragma unroll
            for (int jj = 0; jj < 16; jj++) {
                float v = rintf(src[i + jj] * (127.f / 8.f));
                v = fminf(fmaxf(v, -127.f), 127.f);
                tmp[jj] = (i8)(int)v;
            }
            *(int4v*)&hbuf[0][row * 512 + SWZ8(row, cg + i)] = *(int4v*)tmp;
        }
    }
    if (tid < 32)       xv[0][tid]      = tfeat[(size_t)(b0 + tid) * (T_ * F_) + f];
    else if (tid < 64)  xm[0][tid - 32] = tmask[(size_t)(b0 + tid - 32) * (T_ * F_) + f];

    // c0 -> packed f16 regs: cpk[s][r*2+pi] holds cells p = 2pi, 2pi+1
    f16x2 cpk[4][4];
    #pragma unroll
    for (int s = 0; s < 4; s++) {
        int j = w * 64 + s * 16 + l15;
        #pragma unroll
        for (int r = 0; r < 2; r++) {
            const float* cp = c0 + ((size_t)f * B_ + b0 + r * 16 + lq * 4) * H_ + j;
            #pragma unroll
            for (int pi = 0; pi < 2; pi++)
                cpk[s][r * 2 + pi] = __builtin_amdgcn_cvt_pkrtz(
                    cp[(size_t)(pi * 2) * H_], cp[(size_t)(pi * 2 + 1) * H_]);
        }
    }
    __syncthreads();

    const i8* Wb = Wpk8 + (((size_t)f * 32 + w * 4) << 15);
    const float4* wxbf = (const float4*)wxb4 + (size_t)f * GH_;

    #pragma unroll 1
    for (int t = 0; t < T_; t++) {
        int rb = t & 1, wb = rb ^ 1;
        if (t < T_ - 1) {
            if (tid < 32)      xv[wb][tid]      = tfeat[(size_t)(b0 + tid) * (T_ * F_) + (t + 1) * F_ + f];
            else if (tid < 64) xm[wb][tid - 32] = tmask[(size_t)(b0 + tid - 32) * (T_ * F_) + (t + 1) * F_ + f];
        }
        float hs = (t == 0) ? 8.f : 1.f;
        short* zb = (t == T_ - 1) ? (Z + (size_t)b0 * ZW_ + f * H_) : (short*)nullptr;
        const i8* hr = hbuf[rb];
        i8*       hw = hbuf[wb];
        const float* xvp = xv[rb];
        const float* xmp = xm[rb];
        lstm_step_sub<0>(hr, hw, cpk, Wb, wxbf, xvp, xmp, hs, zb, l, l15, lq, w);
        lstm_step_sub<1>(hr, hw, cpk, Wb, wxbf, xvp, xmp, hs, zb, l, l15, lq, w);
        lstm_step_sub<2>(hr, hw, cpk, Wb, wxbf, xvp, xmp, hs, zb, l, l15, lq, w);
        lstm_step_sub<3>(hr, hw, cpk, Wb, wxbf, xvp, xmp, hs, zb, l, l15, lq, w);
        __syncthreads();
    }
}

// ---------------------------------------------------------------- static MLP
__global__ void k_static(const float* __restrict__ X,
                         const float* __restrict__ sW1T, const float* __restrict__ sb1,
                         const float* __restrict__ sW2T, const float* __restrict__ sb2,
                         const float* __restrict__ sW3T, const float* __restrict__ sb3,
                         short* __restrict__ Z) {
    __shared__ float xs[64], s1[256], s2[256];
    int row = blockIdx.x, tid = threadIdx.x;
    if (tid < 64) xs[tid] = X[row * 64 + tid];
    __syncthreads();
    float a = sb1[tid];
    for (int i = 0; i < 64; i++) a += xs[i] * sW1T[i * 256 + tid];
    s1[tid] = fmaxf(a, 0.f);
    __syncthreads();
    a = sb2[tid];
    for (int i = 0; i < 256; i++) a += s1[i] * sW2T[i * 256 + tid];
    s2[tid] = fmaxf(a, 0.f);
    __syncthreads();
    a = sb3[tid];
    for (int i = 0; i < 256; i++) a += s2[i] * sW3T[i * 256 + tid];
    Z[(size_t)row * ZW_ + F_ * H_ + tid] = f2bf(fmaxf(a, 0.f));
}

// ---------------------------------------------------------------- GEMM + bias + relu
__global__ __launch_bounds__(256, 2)
void k_gemm_relu(const short* __restrict__ A, const short* __restrict__ W,
                 const float* __restrict__ bias, short* __restrict__ C,
                 int M, int N, int K) {
    __shared__ __align__(16) short at[128 * 128];
    int tid = threadIdx.x;
    int wid = tid >> 6, l = tid & 63, l15 = l & 15, lq = l >> 4;
    int wm = wid >> 1, wn = wid & 1;
    int mb = blockIdx.x * 128, nb = blockIdx.y * 128;
    f32x4 acc[4][4];
    #pragma unroll
    for (int n = 0; n < 4; n++)
        #pragma unroll
        for (int r = 0; r < 4; r++)
            acc[n][r] = (f32x4){0.f, 0.f, 0.f, 0.f};

    #pragma unroll 1
    for (int kc = 0; kc < K; kc += 128) {
        {
            int row = tid >> 1, off = (tid & 1) * 64;
            const short* src = A + (size_t)(mb + row) * K + kc + off;
            #pragma unroll
            for (int i = 0; i < 64; i += 8) {
                short8 v = *(const short8*)(src + i);
                int elem = (row * 128 + off + i) ^ ((row & 7) << 3);
                *(short8*)&at[elem] = v;
            }
        }
        __syncthreads();
        #pragma unroll
        for (int kk = 0; kk < 4; kk++) {
            int k = kk * 32 + lq * 8;
            short8 a[4], bfr[4];
            #pragma unroll
            for (int r = 0; r < 4; r++) {
                int row = wm * 64 + 16 * r + l15;
                int elem = (row * 128 + k) ^ ((row & 7) << 3);
                a[r] = *(const short8*)&at[elem];
            }
            #pragma unroll
            for (int n = 0; n < 4; n++)
                bfr[n] = *(const short8*)(W + (size_t)(nb + wn * 64 + 16 * n + l15) * K + kc + k);
            #pragma unroll
            for (int n = 0; n < 4; n++)
                #pragma unroll
                for (int r = 0; r < 4; r++)
                    acc[n][r] = __builtin_amdgcn_mfma_f32_16x16x32_bf16(a[r], bfr[n], acc[n][r], 0, 0, 0);
        }
        __syncthreads();
    }
    #pragma unroll
    for (int n = 0; n < 4; n++) {
        int col = nb + wn * 64 + 16 * n + l15;
        float bv = bias[col];
        #pragma unroll
        for (int r = 0; r < 4; r++)
            #pragma unroll
            for (int p = 0; p < 4; p++) {
                int row = mb + wm * 64 + 16 * r + lq * 4 + p;
                C[(size_t)row * N + col] = f2bf(fmaxf(acc[n][r][p] + bv, 0.f));
            }
    }
}

// ---------------------------------------------------------------- head layer 3 + BCE partials
__global__ void k_head3(const short* __restrict__ Z2, const float* __restrict__ W3,
                        const float* __restrict__ b3, const float* __restrict__ tgt,
                        float* __restrict__ out, float* __restrict__ lsum) {
    __shared__ float ls[32];
    int tid = threadIdx.x, wv = tid >> 6, l = tid & 63;
    int rsub = l >> 3, ks = l & 7;
    int row = blockIdx.x * 32 + wv * 8 + rsub;
    const short* z = Z2 + (size_t)row * 1024 + ks * 128;
    const float* w0 = W3 + ks * 128;
    const float* w1 = W3 + 1024 + ks * 128;
    float a0 = 0.f, a1 = 0.f;
    for (int i = 0; i < 128; i += 8) {
        short8 zv = *(const short8*)(z + i);
        #pragma unroll
        for (int jj = 0; jj < 8; jj++) {
            union { unsigned int u; float f; } cv;
            cv.u = ((unsigned int)(unsigned short)zv[jj]) << 16;
            a0 += cv.f * w0[i + jj];
            a1 += cv.f * w1[i + jj];
        }
    }
    a0 += __shfl_xor(a0, 1); a0 += __shfl_xor(a0, 2); a0 += __shfl_xor(a0, 4);
    a1 += __shfl_xor(a1, 1); a1 += __shfl_xor(a1, 2); a1 += __shfl_xor(a1, 4);
    if (ks == 0) {
        float p0 = fmaxf(a0 + b3[0], 0.f), p1 = fmaxf(a1 + b3[1], 0.f);
        out[row * 2] = p0; out[row * 2 + 1] = p1;
        float t0 = tgt[row * 2], t1 = tgt[row * 2 + 1];
        ls[wv * 8 + rsub] = (p0 - p0 * t0 + __logf(1.f + __expf(-p0)))
                          + (p1 - p1 * t1 + __logf(1.f + __expf(-p1)));
    }
    __syncthreads();
    if (tid == 0) {
        float s = 0.f;
        for (int i = 0; i < 32; i++) s += ls[i];
        lsum[blockIdx.x] = s;
    }
}

__global__ void k_loss_final(const float* __restrict__ lsum, float* __restrict__ out) {
    int l = threadIdx.x;
    float v = lsum[l] + lsum[l + 64];
    for (int m = 1; m < 64; m <<= 1) v += __shfl_xor(v, m);
    if (l == 0) out[B_ * 2] = v / (float)(B_ * 2);
}

// ---------------------------------------------------------------- launch
extern "C" void kernel_launch(void* const* d_in, const int* in_sizes, int n_in,
                              void* d_out, int out_size, void* d_ws, size_t ws_size,
                              hipStream_t stream) {
    const float* sfeat = (const float*)d_in[0];
    const float* tfeat = (const float*)d_in[1];
    const float* tmask = (const float*)d_in[2];
    const float* tgt   = (const float*)d_in[3];
    const float* h0    = (const float*)d_in[4];
    const float* c0    = (const float*)d_in[5];
    const float* Wih   = (const float*)d_in[6];
    const float* Whh   = (const float*)d_in[7];
    const float* bih   = (const float*)d_in[8];
    const float* bhh   = (const float*)d_in[9];
    const float* sW1   = (const float*)d_in[10];
    const float* sb1   = (const float*)d_in[11];
    const float* sW2   = (const float*)d_in[12];
    const float* sb2   = (const float*)d_in[13];
    const float* sW3   = (const float*)d_in[14];
    const float* sb3   = (const float*)d_in[15];
    const float* dW1   = (const float*)d_in[16];
    const float* db1   = (const float*)d_in[17];
    const float* dW2   = (const float*)d_in[18];
    const float* db2   = (const float*)d_in[19];
    const float* dW3   = (const float*)d_in[20];
    const float* db3   = (const float*)d_in[21];

    char* ws = (char*)d_ws;
    size_t off = 0;
    i8*    Wpk8   = (i8*)(ws + off);    off += (size_t)F_ * GH_ * H_;           // 12,582,912
    float* wxb4   = (float*)(ws + off); off += (size_t)F_ * GH_ * 16;           //    786,432
    float* sscale = (float*)(ws + off); off += (size_t)F_ * GH_ * 4;            //     98,304
    short* dW1_bf = (short*)(ws + off); off += (size_t)1024 * ZW_ * 2;          // 13,107,200
    short* dW2_bf = (short*)(ws + off); off += (size_t)1024 * 1024 * 2;         //  2,097,152
    float* sW1T   = (float*)(ws + off); off += (size_t)64 * 256 * 4;
    float* sW2T   = (float*)(ws + off); off += (size_t)256 * 256 * 4;
    float* sW3T   = (float*)(ws + off); off += (size_t)256 * 256 * 4;
    short* Z      = (short*)(ws + off); off += (size_t)B_ * ZW_ * 2;            // 52,428,800
    short* Z1     = (short*)(ws + off); off += (size_t)B_ * 1024 * 2;
    short* Z2     = (short*)(ws + off); off += (size_t)B_ * 1024 * 2;
    float* lsum   = (float*)(ws + off); off += 128 * 4;

    float* out = (float*)d_out;

    k_scales<<<(F_ * GH_ + 255) / 256, 256, 0, stream>>>(Whh, Wih, bih, bhh, sscale, wxb4);
    k_convert<<<2048, 256, 0, stream>>>(Whh, dW1, dW2, sW1, sW2, sW3, sscale,
                                        Wpk8, dW1_bf, dW2_bf, sW1T, sW2T, sW3T);
    k_lstm<<<1536, 512, 0, stream>>>(Wpk8, wxb4, tfeat, tmask, h0, c0, Z);
    k_static<<<4096, 256, 0, stream>>>(sfeat, sW1T, sb1, sW2T, sb2, sW3T, sb3, Z);
    k_gemm_relu<<<dim3(32, 8), 256, 0, stream>>>(Z, dW1_bf, db1, Z1, B_, 1024, ZW_);
    k_gemm_relu<<<dim3(32, 8), 256, 0, stream>>>(Z1, dW2_bf, db2, Z2, B_, 1024, 1024);
    k_head3<<<128, 256, 0, stream>>>(Z2, dW3, db3, tgt, out, lsum);
    k_loss_final<<<1, 64, 0, stream>>>(lsum, out);
}

// Round 22
// 2540.866 us; speedup vs baseline: 2.4410x; 1.0455x over previous
//
#include <hip/hip_runtime.h>
#include <hip/hip_bf16.h>
#include <hip/hip_fp16.h>

#define B_ 4096
#define T_ 24
#define F_ 12
#define H_ 512
#define GH_ 2048   // 4*H
#define ZW_ 6400   // F*H + 256
#define L2E 1.44269504088896340736f

typedef __attribute__((ext_vector_type(8))) short short8;
typedef __attribute__((ext_vector_type(4))) float f32x4;
typedef __attribute__((ext_vector_type(4))) int int4v;
typedef __attribute__((ext_vector_type(2))) __fp16 f16x2;
typedef signed char i8;

// byte-level XOR swizzle, 16B granularity, bijective within a 512-byte row
#define SWZ8(row, byte) ((byte) ^ (((row) & 15) << 4))

__device__ __forceinline__ short f2bf(float f) {
    union { float f; unsigned int u; } v; v.f = f;
    unsigned int u = v.u;
    unsigned int r = (u + 0x7FFFu + ((u >> 16) & 1u)) >> 16;
    return (short)r;
}
__device__ __forceinline__ float fastrcp(float x) { return __builtin_amdgcn_rcpf(x); }
__device__ __forceinline__ float ex2(float x) { return __builtin_amdgcn_exp2f(x); }

// ---------------------------------------------------------------- scales
// One thread per gate-row: s = max|Whh_row|/127; wxb4[row] = (wx0*sc, wx1*sc,
// bias*sc, s*sc/127) with sc = log2e (gate 2: 2*log2e) folded in for ex2.
__global__ void k_scales(const float* Whh, const float* Wih,
                         const float* bih, const float* bhh,
                         float* sscale, float* wxb4) {
    int idx = blockIdx.x * blockDim.x + threadIdx.x;
    if (idx >= F_ * GH_) return;
    int row = idx % GH_;
    int g = row >> 9;
    const float* wr = Whh + (size_t)idx * H_;
    float mx = 1e-8f;
    for (int k = 0; k < H_; k++) mx = fmaxf(mx, fabsf(wr[k]));
    float s = mx * (1.f / 127.f);
    sscale[idx] = s;
    float sc = (g == 2) ? 2.f * L2E : L2E;
    float4 v;
    v.x = Wih[(size_t)idx * 2] * sc;
    v.y = Wih[(size_t)idx * 2 + 1] * sc;
    v.z = (bih[idx] + bhh[idx]) * sc;
    v.w = s * sc * (1.f / 127.f);
    ((float4*)wxb4)[idx] = v;
}

// ---------------------------------------------------------------- convert
// Whh -> int8 MFMA B-fragments (K=64):
//   Wpk8[(((f*32+jb)*8+kk)*4+g)*1024 + l*16 + e]
//     = q( Whh[f][g*512+jb*16+(l&15)][kk*64+(l>>4)*16+e] / s_row )
__global__ void k_convert(const float* Whh, const float* dW1, const float* dW2,
                          const float* sW1, const float* sW2, const float* sW3,
                          const float* sscale,
                          i8* Wpk8, short* odW1, short* odW2,
                          float* sW1T, float* sW2T, float* sW3T) {
    const int N2 = 1024 * ZW_;
    const int N3 = 1024 * 1024;
    const int N4 = F_ * 32 * 8 * 4 * 64;   // 786,432 fragments of 16B
    int idx = blockIdx.x * blockDim.x + threadIdx.x;
    int stride = gridDim.x * blockDim.x;
    for (int i = idx; i < N4; i += stride) {
        int l  = i & 63;
        int g  = (i >> 6) & 3;
        int kk = (i >> 8) & 7;
        int jb = (i >> 11) & 31;
        int f  = i >> 16;
        int row = g * 512 + jb * 16 + (l & 15);
        int col = kk * 64 + (l >> 4) * 16;
        const float* src = Whh + ((size_t)f * GH_ + row) * H_ + col;
        float inv = fastrcp(sscale[f * GH_ + row]);
        i8 tmp[16];
        #pragma unroll
        for (int e = 0; e < 16; e++) {
            float q = rintf(src[e] * inv);
            q = fminf(fmaxf(q, -127.f), 127.f);
            tmp[e] = (i8)(int)q;
        }
        *(int4v*)(Wpk8 + (size_t)i * 16) = *(int4v*)tmp;
    }
    for (int i = idx; i < N2; i += stride) odW1[i] = f2bf(dW1[i]);
    for (int i = idx; i < N3; i += stride) odW2[i] = f2bf(dW2[i]);
    for (int i = idx; i < 64 * 256; i += stride) {
        int r = i >> 8, t = i & 255;
        sW1T[i] = sW1[t * 64 + r];
    }
    for (int i = idx; i < 256 * 256; i += stride) {
        int r = i >> 8, t = i & 255;
        sW2T[i] = sW2[t * 256 + r];
        sW3T[i] = sW3[t * 256 + r];
    }
}

// ---------------------------------------------------------------- LSTM sub-step
// One 16-col j-subtile for one wave, 32-row tile (2 rowfrags), int8 K=64:
// 8 kk x 4 gates x 2 rf = 64 MFMA per subtile; i32 exact accumulation;
// dequant + exact f32 x-part/bias in epilogue (wxb4); kk unroll 2 (HARD CAP).
// LAST is compile-time: removes the per-cell Z-branch from 23 of 24 steps.
template<int S, bool LAST>
__device__ __forceinline__ void lstm_step_sub(
    const i8* hread, i8* hwrite, f16x2 (&cpk)[4][4],
    const i8* Wb, const float4* wxbf,
    const float* xvp, const float* xmp,
    float hs, short* zb,
    int l, int l15, int lq, int w)
{
    const i8* Ws = Wb + ((size_t)S << 15) + l * 16;   // 8kk*4g*1KB per subtile
    int j = w * 64 + S * 16 + l15;
    // hoist dequant/x-part params: loads fly under the MFMA stream
    float4 wb0 = wxbf[0 * 512 + j], wb1 = wxbf[1 * 512 + j];
    float4 wb2 = wxbf[2 * 512 + j], wb3 = wxbf[3 * 512 + j];
    int4v acc[4][2];
    #pragma unroll
    for (int g = 0; g < 4; g++)
        #pragma unroll
        for (int r = 0; r < 2; r++)
            acc[g][r] = (int4v){0, 0, 0, 0};
    #pragma unroll 2
    for (int kk = 0; kk < 8; kk++) {
        int k = kk * 64 + lq * 16;
        int4v a[2], bfr[4];
        #pragma unroll
        for (int r = 0; r < 2; r++) {
            int row = r * 16 + l15;
            a[r] = *(const int4v*)&hread[row * 512 + SWZ8(row, k)];
        }
        #pragma unroll
        for (int g = 0; g < 4; g++)
            bfr[g] = *(const int4v*)(Ws + (kk * 4 + g) * 1024);
        #pragma unroll
        for (int g = 0; g < 4; g++)
            #pragma unroll
            for (int r = 0; r < 2; r++)
                acc[g][r] = __builtin_amdgcn_mfma_i32_16x16x64_i8(a[r], bfr[g], acc[g][r], 0, 0, 0);
    }
    float d0 = wb0.w * hs, d1 = wb1.w * hs, d2 = wb2.w * hs, d3 = wb3.w * hs;
    #pragma unroll
    for (int r = 0; r < 2; r++) {
        #pragma unroll
        for (int pi = 0; pi < 2; pi++) {
            f16x2 cold = cpk[S][r * 2 + pi];
            float cn01[2];
            #pragma unroll
            for (int q = 0; q < 2; q++) {
                int p = pi * 2 + q;
                int row = r * 16 + lq * 4 + p;
                float xvf = xvp[row], xmf = xmp[row];
                float iv = (float)acc[0][r][p] * d0 + wb0.x * xvf + wb0.y * xmf + wb0.z;
                float fv = (float)acc[1][r][p] * d1 + wb1.x * xvf + wb1.y * xmf + wb1.z;
                float gv = (float)acc[2][r][p] * d2 + wb2.x * xvf + wb2.y * xmf + wb2.z;
                float ov = (float)acc[3][r][p] * d3 + wb3.x * xvf + wb3.y * xmf + wb3.z;
                float ef = ex2(fv), ei = ex2(iv), eg = ex2(gv);
                float ef1 = ef + 1.f, ei1 = ei + 1.f, eg1 = eg + 1.f;
                float e12 = ei1 * eg1;
                float cn = (ef * e12 * (float)cold[q] + ei * (eg - 1.f) * ef1)
                         * fastrcp(ef1 * e12);
                cn01[q] = cn;
                float eo = ex2(ov), ec = ex2(cn * (2.f * L2E));
                float hn = eo * (ec - 1.f) * fastrcp((eo + 1.f) * (ec + 1.f));
                hwrite[row * 512 + SWZ8(row, j)] = (i8)(int)rintf(hn * 127.f);
                if (LAST) zb[(size_t)row * ZW_ + j] = f2bf(hn);   // exact bf16 -> Z
            }
            cpk[S][r * 2 + pi] = __builtin_amdgcn_cvt_pkrtz(cn01[0], cn01[1]);
        }
    }
}

template<bool LAST>
__device__ __forceinline__ void lstm_step(
    const i8* hr, i8* hw, f16x2 (&cpk)[4][4],
    const i8* Wb, const float4* wxbf,
    const float* xvp, const float* xmp,
    float hs, short* zb, int l, int l15, int lq, int w)
{
    lstm_step_sub<0, LAST>(hr, hw, cpk, Wb, wxbf, xvp, xmp, hs, zb, l, l15, lq, w);
    lstm_step_sub<1, LAST>(hr, hw, cpk, Wb, wxbf, xvp, xmp, hs, zb, l, l15, lq, w);
    lstm_step_sub<2, LAST>(hr, hw, cpk, Wb, wxbf, xvp, xmp, hs, zb, l, l15, lq, w);
    lstm_step_sub<3, LAST>(hr, hw, cpk, Wb, wxbf, xvp, xmp, hs, zb, l, l15, lq, w);
}

// grid 1536 (12 features x 128 batch-tiles of 32 rows), 512 threads (8 waves).
// h double-buffered int8 in LDS (2x16KB, swizzled); c in 16 packed-f16 regs;
// weights int8 (HALVED L2 stream vs bf16: 36.9GB total) in packed K=64
// fragment order; i32 MFMA accumulation (exact); exact f32 x-part in epilogue.
// h0 (unbounded randn) uses scale 8/127 on t=0 only (hs multiplier).
__global__ __launch_bounds__(512, 2)
void k_lstm(const i8* __restrict__ Wpk8,
            const float* __restrict__ wxb4,  // [F*2048] float4: wx0,wx1,bias,dequant
            const float* __restrict__ tfeat, // [B][T][F]
            const float* __restrict__ tmask,
            const float* __restrict__ h0,    // [F][B][H]
            const float* __restrict__ c0,
            short* __restrict__ Z)           // [B][6400] bf16
{
    __shared__ __align__(16) i8 hbuf[2][32 * 512];   // 2 x 16KB
    __shared__ float xv[2][32], xm[2][32];

    int bid = blockIdx.x;
    int wg = (bid & 7) * 192 + (bid >> 3);   // XCD swizzle (1536 = 8*192, bijective)
    int f = wg >> 7;
    int b0 = (wg & 127) * 32;
    int tid = threadIdx.x;
    int w = tid >> 6;
    int l = tid & 63;
    int l15 = l & 15, lq = l >> 4;

    // stage h0 -> hbuf[0] (int8, scale 8/127, swizzled): 32 rows x 512 cols
    {
        int row = tid >> 4, cg = (tid & 15) * 32;
        const float* src = h0 + ((size_t)f * B_ + b0 + row) * H_ + cg;
        #pragma unroll
        for (int i = 0; i < 32; i += 16) {
            float4 v4[4];
            #pragma unroll
            for (int u = 0; u < 4; u++) v4[u] = ((const float4*)(src + i))[u];
            i8 tmp[16];
            #pragma unroll
            for (int u = 0; u < 4; u++) {
                const float* pv = (const float*)&v4[u];
                #pragma unroll
                for (int jj = 0; jj < 4; jj++) {
                    float v = rintf(pv[jj] * (127.f / 8.f));
                    v = fminf(fmaxf(v, -127.f), 127.f);
                    tmp[u * 4 + jj] = (i8)(int)v;
                }
            }
            *(int4v*)&hbuf[0][row * 512 + SWZ8(row, cg + i)] = *(int4v*)tmp;
        }
    }
    if (tid < 32)       xv[0][tid]      = tfeat[(size_t)(b0 + tid) * (T_ * F_) + f];
    else if (tid < 64)  xm[0][tid - 32] = tmask[(size_t)(b0 + tid - 32) * (T_ * F_) + f];

    // c0 -> packed f16 regs: cpk[s][r*2+pi] holds cells p = 2pi, 2pi+1
    f16x2 cpk[4][4];
    #pragma unroll
    for (int s = 0; s < 4; s++) {
        int j = w * 64 + s * 16 + l15;
        #pragma unroll
        for (int r = 0; r < 2; r++) {
            const float* cp = c0 + ((size_t)f * B_ + b0 + r * 16 + lq * 4) * H_ + j;
            #pragma unroll
            for (int pi = 0; pi < 2; pi++)
                cpk[s][r * 2 + pi] = __builtin_amdgcn_cvt_pkrtz(
                    cp[(size_t)(pi * 2) * H_], cp[(size_t)(pi * 2 + 1) * H_]);
        }
    }
    __syncthreads();

    const i8* Wb = Wpk8 + (((size_t)f * 32 + w * 4) << 15);
    const float4* wxbf = (const float4*)wxb4 + (size_t)f * GH_;
    short* zbase = Z + (size_t)b0 * ZW_ + f * H_;

    #pragma unroll 1
    for (int t = 0; t < T_ - 1; t++) {
        int rb = t & 1, wb = rb ^ 1;
        if (tid < 32)      xv[wb][tid]      = tfeat[(size_t)(b0 + tid) * (T_ * F_) + (t + 1) * F_ + f];
        else if (tid < 64) xm[wb][tid - 32] = tmask[(size_t)(b0 + tid - 32) * (T_ * F_) + (t + 1) * F_ + f];
        float hs = (t == 0) ? 8.f : 1.f;
        lstm_step<false>(hbuf[rb], hbuf[wb], cpk, Wb, wxbf, xv[rb], xm[rb],
                         hs, nullptr, l, l15, lq, w);
        __syncthreads();
    }
    {   // final step: T-1 is odd (rb=1), exact bf16 h -> Z
        int rb = (T_ - 1) & 1, wb = rb ^ 1;
        lstm_step<true>(hbuf[rb], hbuf[wb], cpk, Wb, wxbf, xv[rb], xm[rb],
                        1.f, zbase, l, l15, lq, w);
    }
}

// ---------------------------------------------------------------- static MLP
__global__ void k_static(const float* __restrict__ X,
                         const float* __restrict__ sW1T, const float* __restrict__ sb1,
                         const float* __restrict__ sW2T, const float* __restrict__ sb2,
                         const float* __restrict__ sW3T, const float* __restrict__ sb3,
                         short* __restrict__ Z) {
    __shared__ float xs[64], s1[256], s2[256];
    int row = blockIdx.x, tid = threadIdx.x;
    if (tid < 64) xs[tid] = X[row * 64 + tid];
    __syncthreads();
    float a = sb1[tid];
    for (int i = 0; i < 64; i++) a += xs[i] * sW1T[i * 256 + tid];
    s1[tid] = fmaxf(a, 0.f);
    __syncthreads();
    a = sb2[tid];
    for (int i = 0; i < 256; i++) a += s1[i] * sW2T[i * 256 + tid];
    s2[tid] = fmaxf(a, 0.f);
    __syncthreads();
    a = sb3[tid];
    for (int i = 0; i < 256; i++) a += s2[i] * sW3T[i * 256 + tid];
    Z[(size_t)row * ZW_ + F_ * H_ + tid] = f2bf(fmaxf(a, 0.f));
}

// ---------------------------------------------------------------- GEMM + bias + relu
__global__ __launch_bounds__(256, 2)
void k_gemm_relu(const short* __restrict__ A, const short* __restrict__ W,
                 const float* __restrict__ bias, short* __restrict__ C,
                 int M, int N, int K) {
    __shared__ __align__(16) short at[128 * 128];
    int tid = threadIdx.x;
    int wid = tid >> 6, l = tid & 63, l15 = l & 15, lq = l >> 4;
    int wm = wid >> 1, wn = wid & 1;
    int mb = blockIdx.x * 128, nb = blockIdx.y * 128;
    f32x4 acc[4][4];
    #pragma unroll
    for (int n = 0; n < 4; n++)
        #pragma unroll
        for (int r = 0; r < 4; r++)
            acc[n][r] = (f32x4){0.f, 0.f, 0.f, 0.f};

    #pragma unroll 1
    for (int kc = 0; kc < K; kc += 128) {
        {
            int row = tid >> 1, off = (tid & 1) * 64;
            const short* src = A + (size_t)(mb + row) * K + kc + off;
            #pragma unroll
            for (int i = 0; i < 64; i += 8) {
                short8 v = *(const short8*)(src + i);
                int elem = (row * 128 + off + i) ^ ((row & 7) << 3);
                *(short8*)&at[elem] = v;
            }
        }
        __syncthreads();
        #pragma unroll
        for (int kk = 0; kk < 4; kk++) {
            int k = kk * 32 + lq * 8;
            short8 a[4], bfr[4];
            #pragma unroll
            for (int r = 0; r < 4; r++) {
                int row = wm * 64 + 16 * r + l15;
                int elem = (row * 128 + k) ^ ((row & 7) << 3);
                a[r] = *(const short8*)&at[elem];
            }
            #pragma unroll
            for (int n = 0; n < 4; n++)
                bfr[n] = *(const short8*)(W + (size_t)(nb + wn * 64 + 16 * n + l15) * K + kc + k);
            #pragma unroll
            for (int n = 0; n < 4; n++)
                #pragma unroll
                for (int r = 0; r < 4; r++)
                    acc[n][r] = __builtin_amdgcn_mfma_f32_16x16x32_bf16(a[r], bfr[n], acc[n][r], 0, 0, 0);
        }
        __syncthreads();
    }
    #pragma unroll
    for (int n = 0; n < 4; n++) {
        int col = nb + wn * 64 + 16 * n + l15;
        float bv = bias[col];
        #pragma unroll
        for (int r = 0; r < 4; r++)
            #pragma unroll
            for (int p = 0; p < 4; p++) {
                int row = mb + wm * 64 + 16 * r + lq * 4 + p;
                C[(size_t)row * N + col] = f2bf(fmaxf(acc[n][r][p] + bv, 0.f));
            }
    }
}

// ---------------------------------------------------------------- head layer 3 + BCE partials
__global__ void k_head3(const short* __restrict__ Z2, const float* __restrict__ W3,
                        const float* __restrict__ b3, const float* __restrict__ tgt,
                        float* __restrict__ out, float* __restrict__ lsum) {
    __shared__ float ls[32];
    int tid = threadIdx.x, wv = tid >> 6, l = tid & 63;
    int rsub = l >> 3, ks = l & 7;
    int row = blockIdx.x * 32 + wv * 8 + rsub;
    const short* z = Z2 + (size_t)row * 1024 + ks * 128;
    const float* w0 = W3 + ks * 128;
    const float* w1 = W3 + 1024 + ks * 128;
    float a0 = 0.f, a1 = 0.f;
    for (int i = 0; i < 128; i += 8) {
        short8 zv = *(const short8*)(z + i);
        #pragma unroll
        for (int jj = 0; jj < 8; jj++) {
            union { unsigned int u; float f; } cv;
            cv.u = ((unsigned int)(unsigned short)zv[jj]) << 16;
            a0 += cv.f * w0[i + jj];
            a1 += cv.f * w1[i + jj];
        }
    }
    a0 += __shfl_xor(a0, 1); a0 += __shfl_xor(a0, 2); a0 += __shfl_xor(a0, 4);
    a1 += __shfl_xor(a1, 1); a1 += __shfl_xor(a1, 2); a1 += __shfl_xor(a1, 4);
    if (ks == 0) {
        float p0 = fmaxf(a0 + b3[0], 0.f), p1 = fmaxf(a1 + b3[1], 0.f);
        out[row * 2] = p0; out[row * 2 + 1] = p1;
        float t0 = tgt[row * 2], t1 = tgt[row * 2 + 1];
        ls[wv * 8 + rsub] = (p0 - p0 * t0 + __logf(1.f + __expf(-p0)))
                          + (p1 - p1 * t1 + __logf(1.f + __expf(-p1)));
    }
    __syncthreads();
    if (tid == 0) {
        float s = 0.f;
        for (int i = 0; i < 32; i++) s += ls[i];
        lsum[blockIdx.x] = s;
    }
}

__global__ void k_loss_final(const float* __restrict__ lsum, float* __restrict__ out) {
    int l = threadIdx.x;
    float v = lsum[l] + lsum[l + 64];
    for (int m = 1; m < 64; m <<= 1) v += __shfl_xor(v, m);
    if (l == 0) out[B_ * 2] = v / (float)(B_ * 2);
}

// ---------------------------------------------------------------- launch
extern "C" void kernel_launch(void* const* d_in, const int* in_sizes, int n_in,
                              void* d_out, int out_size, void* d_ws, size_t ws_size,
                              hipStream_t stream) {
    const float* sfeat = (const float*)d_in[0];
    const float* tfeat = (const float*)d_in[1];
    const float* tmask = (const float*)d_in[2];
    const float* tgt   = (const float*)d_in[3];
    const float* h0    = (const float*)d_in[4];
    const float* c0    = (const float*)d_in[5];
    const float* Wih   = (const float*)d_in[6];
    const float* Whh   = (const float*)d_in[7];
    const float* bih   = (const float*)d_in[8];
    const float* bhh   = (const float*)d_in[9];
    const float* sW1   = (const float*)d_in[10];
    const float* sb1   = (const float*)d_in[11];
    const float* sW2   = (const float*)d_in[12];
    const float* sb2   = (const float*)d_in[13];
    const float* sW3   = (const float*)d_in[14];
    const float* sb3   = (const float*)d_in[15];
    const float* dW1   = (const float*)d_in[16];
    const float* db1   = (const float*)d_in[17];
    const float* dW2   = (const float*)d_in[18];
    const float* db2   = (const float*)d_in[19];
    const float* dW3   = (const float*)d_in[20];
    const float* db3   = (const float*)d_in[21];

    char* ws = (char*)d_ws;
    size_t off = 0;
    i8*    Wpk8   = (i8*)(ws + off);    off += (size_t)F_ * GH_ * H_;           // 12,582,912
    float* wxb4   = (float*)(ws + off); off += (size_t)F_ * GH_ * 16;           //    786,432
    float* sscale = (float*)(ws + off); off += (size_t)F_ * GH_ * 4;            //     98,304
    short* dW1_bf = (short*)(ws + off); off += (size_t)1024 * ZW_ * 2;          // 13,107,200
    short* dW2_bf = (short*)(ws + off); off += (size_t)1024 * 1024 * 2;         //  2,097,152
    float* sW1T   = (float*)(ws + off); off += (size_t)64 * 256 * 4;
    float* sW2T   = (float*)(ws + off); off += (size_t)256 * 256 * 4;
    float* sW3T   = (float*)(ws + off); off += (size_t)256 * 256 * 4;
    short* Z      = (short*)(ws + off); off += (size_t)B_ * ZW_ * 2;            // 52,428,800
    short* Z1     = (short*)(ws + off); off += (size_t)B_ * 1024 * 2;
    short* Z2     = (short*)(ws + off); off += (size_t)B_ * 1024 * 2;
    float* lsum   = (float*)(ws + off); off += 128 * 4;

    float* out = (float*)d_out;

    k_scales<<<(F_ * GH_ + 255) / 256, 256, 0, stream>>>(Whh, Wih, bih, bhh, sscale, wxb4);
    k_convert<<<2048, 256, 0, stream>>>(Whh, dW1, dW2, sW1, sW2, sW3, sscale,
                                        Wpk8, dW1_bf, dW2_bf, sW1T, sW2T, sW3T);
    k_lstm<<<1536, 512, 0, stream>>>(Wpk8, wxb4, tfeat, tmask, h0, c0, Z);
    k_static<<<4096, 256, 0, stream>>>(sfeat, sW1T, sb1, sW2T, sb2, sW3T, sb3, Z);
    k_gemm_relu<<<dim3(32, 8), 256, 0, stream>>>(Z, dW1_bf, db1, Z1, B_, 1024, ZW_);
    k_gemm_relu<<<dim3(32, 8), 256, 0, stream>>>(Z1, dW2_bf, db2, Z2, B_, 1024, 1024);
    k_head3<<<128, 256, 0, stream>>>(Z2, dW3, db3, tgt, out, lsum);
    k_loss_final<<<1, 64, 0, stream>>>(lsum, out);
}